// Round 14
// baseline (232.259 us; speedup 1.0000x reference)
//
#include <hip/hip_runtime.h>
#include <hip/hip_fp16.h>

#define NROWS 32768
#define DIMS 256
#define KCODES 8192
#define NH 2            // K-halves (grid = 128 rowblks x 2 halves = 256 blocks)
#define HCODES 4096
#define NT 32           // 128-code tiles per half (r14: halves barrier count)
#define MARGIN 0.10f

typedef _Float16 half8 __attribute__((ext_vector_type(8)));
typedef _Float16 half4 __attribute__((ext_vector_type(4)));
typedef float f32x4 __attribute__((ext_vector_type(4)));
typedef unsigned long long u64;

__device__ __forceinline__ void gload_lds16(const void* g, void* l) {
  __builtin_amdgcn_global_load_lds((const __attribute__((address_space(1))) unsigned int*)g,
                                   (__attribute__((address_space(3))) unsigned int*)l, 16, 0, 0);
}

__device__ __forceinline__ unsigned sortable_f32(float f) {
  unsigned u = __float_as_uint(f);
  return u ^ (unsigned)(((int)u >> 31) | 0x80000000);
}
__device__ __forceinline__ float unsortable_f32(unsigned s) {
  const unsigned m = ((int)s < 0) ? 0x80000000u : 0xFFFFFFFFu;
  return __uint_as_float(s ^ m);
}
__device__ __forceinline__ u64 umin64(u64 a, u64 b) { return a < b ? a : b; }
__device__ __forceinline__ u64 umax64(u64 a, u64 b) { return a > b ? a : b; }
__device__ __forceinline__ float dkey(u64 k) { return unsortable_f32((unsigned)(k >> 32)); }

// ---------------------------------------------------------------------------
// K0 (fused): cb -> f16 codebook + squared norms + zero counters, one pass.
// 2048 blocks x 256 thr; one wave per code (64 lanes x float4).
// ---------------------------------------------------------------------------
__global__ void k_prep2(const float* __restrict__ cb, _Float16* __restrict__ cbh,
                        float* __restrict__ cnorm, int* __restrict__ wcount,
                        int* __restrict__ scount, float* __restrict__ loss_cell) {
  const int lane = threadIdx.x & 63;
  const int code = blockIdx.x * 4 + (threadIdx.x >> 6);
  const float4 v = *((const float4*)(cb + (size_t)code * DIMS) + lane);
  half4 h;
  h[0] = (_Float16)v.x; h[1] = (_Float16)v.y;
  h[2] = (_Float16)v.z; h[3] = (_Float16)v.w;
  *((half4*)(cbh + (size_t)code * DIMS) + lane) = h;
  float s = v.x * v.x + v.y * v.y + v.z * v.z + v.w * v.w;
#pragma unroll
  for (int m = 1; m < 64; m <<= 1) s += __shfl_xor(s, m);
  if (lane == 0) cnorm[code] = s;
  if (blockIdx.x == 0 && threadIdx.x == 0) {
    *wcount = 0; *scount = 0; *loss_cell = 0.0f;
  }
}

// ---------------------------------------------------------------------------
// K1 (fallback path only): norms + zero counters.
// ---------------------------------------------------------------------------
__global__ void k_cnorm(const float* __restrict__ cb, float* __restrict__ cnorm,
                        int* __restrict__ wcount, int* __restrict__ scount,
                        float* __restrict__ loss_cell) {
  const int lane = threadIdx.x & 63;
  const int code = blockIdx.x * 4 + (threadIdx.x >> 6);
  const float4 v = *((const float4*)(cb + code * DIMS) + lane);
  float s = v.x * v.x + v.y * v.y + v.z * v.z + v.w * v.w;
#pragma unroll
  for (int m = 1; m < 64; m <<= 1) s += __shfl_xor(s, m);
  if (lane == 0) cnorm[code] = s;
  if (blockIdx.x == 0 && threadIdx.x == 0) {
    *wcount = 0; *scount = 0; *loss_cell = 0.0f;
  }
}

// ---------------------------------------------------------------------------
// K2 (fast): r9's measured-best structure with 128-code tiles (r14): same
// MFMA/ds_read/epilogue counts per wave, HALF the barriers (64 vs 128).
// Grid 256 = 1 block/CU (LDS 128KB irrelevant to occupancy). Same dbuf
// __syncthreads semantics as the verified template — only tile width changed.
// 3-key butterfly: k1=(val,idx), k2=(val,SENTINEL), k3=INF.
// Ledger: M_rep=4 (-13%), acc-pipe (-17%), counted-vmcnt (RACED) all lost.
// ---------------------------------------------------------------------------
__launch_bounds__(512)
__global__ void k_gemm2(const float* __restrict__ x, const _Float16* __restrict__ cbh,
                        const float* __restrict__ cnorm,
                        u64* __restrict__ pk1, u64* __restrict__ pk2,
                        float* __restrict__ d3h) {
  __shared__ char B[2][65536];
  const int tid = threadIdx.x;
  const int lane = tid & 63;
  const int w = tid >> 6;
  const int l15 = lane & 15;
  const int lh = lane >> 4;
  const int rowblk = (int)blockIdx.x >> 1;
  const int half = (int)blockIdx.x & 1;
  const int row0 = rowblk * 256 + w * 32;
  const char* cbh_half = (const char*)(cbh + (size_t)half * HCODES * DIMS);

  half8 a[2][8];
#pragma unroll
  for (int m = 0; m < 2; ++m) {
#pragma unroll
    for (int kf = 0; kf < 8; ++kf) {
      const float* s = x + (size_t)(row0 + m * 16 + l15) * DIMS + kf * 32 + lh * 8;
      const float4 v0 = *(const float4*)s;
      const float4 v1 = *(const float4*)(s + 4);
      half8 h;
      h[0] = (_Float16)v0.x; h[1] = (_Float16)v0.y;
      h[2] = (_Float16)v0.z; h[3] = (_Float16)v0.w;
      h[4] = (_Float16)v1.x; h[5] = (_Float16)v1.y;
      h[6] = (_Float16)v1.z; h[7] = (_Float16)v1.w;
      a[m][kf] = h;
    }
  }

  // Tile = 128 codes x 256 dims f16 = 64KB = 4096 granules of 16B.
  // Granule L = (ch*4+lh2)*128 + (code ^ ((lh2&1)<<4)); thread stages 8.
  int srcoff[8];
#pragma unroll
  for (int i = 0; i < 8; ++i) {
    const int L = i * 512 + tid;
    const int hi = L >> 7;
    const int lhL = hi & 3, chL = hi >> 2;
    const int code = (L & 127) ^ ((lhL & 1) << 4);
    srcoff[i] = code * 512 + chL * 64 + lhL * 16;
  }

  const int lanebase = l15 * 16 + lh * 2048;
  const int bs = (lh & 1) << 8;
  const int lbp = lanebase + bs;
  const int lbm = lanebase - bs;

  float r1[2][4], r2[2][4];
  int i1[2][4];
#pragma unroll
  for (int m = 0; m < 2; ++m)
#pragma unroll
    for (int j = 0; j < 4; ++j) { r1[m][j] = 3.0e38f; r2[m][j] = 3.0e38f; i1[m][j] = 0; }

  char* lds = &B[0][0];

  auto stage = [&](int t, int bufoff) {
#pragma unroll
    for (int i = 0; i < 8; ++i)
      gload_lds16(cbh_half + t * 65536 + srcoff[i],
                  lds + bufoff + (i * 512 + w * 64) * 16);
  };

  auto compute_tile = [&](int t, int bufoff) {
    const int cbase = half * HCODES + t * 128;
    float cn[8];
#pragma unroll
    for (int n = 0; n < 8; ++n) cn[n] = cnorm[cbase + n * 16 + l15];
    f32x4 acc[2][8];
#pragma unroll
    for (int m = 0; m < 2; ++m)
#pragma unroll
      for (int n = 0; n < 8; ++n) acc[m][n] = (f32x4){0.f, 0.f, 0.f, 0.f};
#pragma unroll
    for (int ch = 0; ch < 8; ++ch) {
      half8 b[8];
#pragma unroll
      for (int n = 0; n < 8; ++n) {
        const int ad = ((n & 1) ? lbm : lbp) + bufoff + ch * 8192 + n * 256;
        b[n] = *(const half8*)(lds + ad);
      }
#pragma unroll
      for (int m = 0; m < 2; ++m)
#pragma unroll
        for (int n = 0; n < 8; ++n)
          acc[m][n] = __builtin_amdgcn_mfma_f32_16x16x32_f16(a[m][ch], b[n], acc[m][n], 0, 0, 0);
    }
#pragma unroll
    for (int m = 0; m < 2; ++m)
#pragma unroll
      for (int n = 0; n < 8; ++n) {
        const int ic = t * 8 + n;
#pragma unroll
        for (int j = 0; j < 4; ++j) {
          const float d = fmaf(-2.0f, acc[m][n][j], cn[n]);
          const bool lt1 = d < r1[m][j];
          r2[m][j] = __builtin_amdgcn_fmed3f(d, r1[m][j], r2[m][j]);
          i1[m][j] = lt1 ? ic : i1[m][j];
          r1[m][j] = fminf(d, r1[m][j]);
        }
      }
  };

  stage(0, 0);
#pragma unroll 1
  for (int t = 0; t < NT; t += 2) {
    __syncthreads();
    if (t + 1 < NT) stage(t + 1, 65536);
    compute_tile(t, 0);
    __syncthreads();
    if (t + 2 < NT) stage(t + 2, 0);
    compute_tile(t + 1, 65536);
  }

  // 3-key butterfly: k1=(val,idx), k2=(val,SENTINEL), k3=INF.
#pragma unroll
  for (int m = 0; m < 2; ++m)
#pragma unroll
    for (int j = 0; j < 4; ++j) {
      const int ia = i1[m][j];
      const unsigned c1 = half * HCODES + (ia >> 3) * 128 + (ia & 7) * 16 + l15;
      u64 k1 = ((u64)sortable_f32(r1[m][j]) << 32) | c1;
      u64 k2 = ((u64)sortable_f32(r2[m][j]) << 32) | 0xffffffffu;
      u64 k3 = ~0ull;
#pragma unroll
      for (int mk = 1; mk < 16; mk <<= 1) {
        const u64 o1 = __shfl_xor(k1, mk);
        const u64 o2 = __shfl_xor(k2, mk);
        const u64 o3 = __shfl_xor(k3, mk);
        const u64 hi1 = umax64(k1, o1);
        k3 = umin64(umin64(k3, o3), umin64(umax64(k1, o2), umax64(k2, o1)));
        k2 = umin64(hi1, umin64(k2, o2));
        k1 = umin64(k1, o1);
      }
      if (l15 == 0) {
        const int rg = row0 + m * 16 + lh * 4 + j;
        pk1[half * NROWS + rg] = k1;
        pk2[half * NROWS + rg] = k2;
        d3h[half * NROWS + rg] = dkey(k3);
      }
    }
}

// ---------------------------------------------------------------------------
// K2 (fallback, ws too small): in-kernel convert, padded LDS, same outputs.
// ---------------------------------------------------------------------------
__launch_bounds__(512)
__global__ void k_gemm_fb(const float* __restrict__ x, const float* __restrict__ cb,
                          const float* __restrict__ cnorm,
                          u64* __restrict__ pk1, u64* __restrict__ pk2,
                          float* __restrict__ d3h) {
  __shared__ _Float16 clds[128][40];
  const int tid = threadIdx.x;
  const int lane = tid & 63;
  const int w = tid >> 6;
  const int l15 = lane & 15;
  const int lh = lane >> 4;
  const int rowblk = (int)blockIdx.x >> 1;
  const int half = (int)blockIdx.x & 1;
  const int row0 = rowblk * 256 + w * 32;

  half8 a[2][8];
#pragma unroll
  for (int m = 0; m < 2; ++m) {
#pragma unroll
    for (int kf = 0; kf < 8; ++kf) {
      const float* s = x + (row0 + m * 16 + l15) * DIMS + kf * 32 + lh * 8;
      const float4 v0 = *(const float4*)s;
      const float4 v1 = *(const float4*)(s + 4);
      half8 h;
      h[0] = (_Float16)v0.x; h[1] = (_Float16)v0.y;
      h[2] = (_Float16)v0.z; h[3] = (_Float16)v0.w;
      h[4] = (_Float16)v1.x; h[5] = (_Float16)v1.y;
      h[6] = (_Float16)v1.z; h[7] = (_Float16)v1.w;
      a[m][kf] = h;
    }
  }

  float r1[2][4], r2[2][4];
  int i1[2][4];
#pragma unroll
  for (int m = 0; m < 2; ++m)
#pragma unroll
    for (int j = 0; j < 4; ++j) { r1[m][j] = 3.0e38f; r2[m][j] = 3.0e38f; i1[m][j] = 0; }

  const int stg_code = tid >> 2;
  const int stg_seg = tid & 3;

  for (int ct = 0; ct < 32; ++ct) {
    const int cbase = half * HCODES + ct * 128;
    f32x4 acc[2][8];
#pragma unroll
    for (int m = 0; m < 2; ++m)
#pragma unroll
      for (int n = 0; n < 8; ++n) acc[m][n] = (f32x4){0.f, 0.f, 0.f, 0.f};

#pragma unroll
    for (int ch = 0; ch < 8; ++ch) {
      __syncthreads();
      {
        const float* s = cb + (cbase + stg_code) * DIMS + ch * 32 + stg_seg * 8;
        const float4 v0 = *(const float4*)s;
        const float4 v1 = *(const float4*)(s + 4);
        half8 h;
        h[0] = (_Float16)v0.x; h[1] = (_Float16)v0.y;
        h[2] = (_Float16)v0.z; h[3] = (_Float16)v0.w;
        h[4] = (_Float16)v1.x; h[5] = (_Float16)v1.y;
        h[6] = (_Float16)v1.z; h[7] = (_Float16)v1.w;
        *(half8*)&clds[stg_code][stg_seg * 8] = h;
      }
      __syncthreads();
      half8 b[8];
#pragma unroll
      for (int n = 0; n < 8; ++n)
        b[n] = *(const half8*)&clds[n * 16 + l15][lh * 8];
#pragma unroll
      for (int m = 0; m < 2; ++m)
#pragma unroll
        for (int n = 0; n < 8; ++n)
          acc[m][n] = __builtin_amdgcn_mfma_f32_16x16x32_f16(a[m][ch], b[n], acc[m][n], 0, 0, 0);
    }

    float cn[8];
#pragma unroll
    for (int n = 0; n < 8; ++n) cn[n] = cnorm[cbase + n * 16 + l15];
#pragma unroll
    for (int m = 0; m < 2; ++m)
#pragma unroll
      for (int n = 0; n < 8; ++n) {
        const int ic = ct * 8 + n;
#pragma unroll
        for (int j = 0; j < 4; ++j) {
          const float d = fmaf(-2.0f, acc[m][n][j], cn[n]);
          const bool lt1 = d < r1[m][j];
          r2[m][j] = __builtin_amdgcn_fmed3f(d, r1[m][j], r2[m][j]);
          i1[m][j] = lt1 ? ic : i1[m][j];
          r1[m][j] = fminf(d, r1[m][j]);
        }
      }
  }

#pragma unroll
  for (int m = 0; m < 2; ++m)
#pragma unroll
    for (int j = 0; j < 4; ++j) {
      const int ia = i1[m][j];
      const unsigned c1 = half * HCODES + (ia >> 3) * 128 + (ia & 7) * 16 + l15;
      u64 k1 = ((u64)sortable_f32(r1[m][j]) << 32) | c1;
      u64 k2 = ((u64)sortable_f32(r2[m][j]) << 32) | 0xffffffffu;
      u64 k3 = ~0ull;
#pragma unroll
      for (int mk = 1; mk < 16; mk <<= 1) {
        const u64 o1 = __shfl_xor(k1, mk);
        const u64 o2 = __shfl_xor(k2, mk);
        const u64 o3 = __shfl_xor(k3, mk);
        const u64 hi1 = umax64(k1, o1);
        k3 = umin64(umin64(k3, o3), umin64(umax64(k1, o2), umax64(k2, o1)));
        k2 = umin64(hi1, umin64(k2, o2));
        k1 = umin64(k1, o1);
      }
      if (l15 == 0) {
        const int rg = row0 + m * 16 + lh * 4 + j;
        pk1[half * NROWS + rg] = k1;
        pk2[half * NROWS + rg] = k2;
        d3h[half * NROWS + rg] = dkey(k3);
      }
    }
}

// ---------------------------------------------------------------------------
// K3: fold halves; classify clean / soft (2-candidate) / hard (full scan).
// hard = 3-way tie (d3) OR ambiguous-without-idx2 (sentinel collision).
// ---------------------------------------------------------------------------
__global__ void k_merge(const u64* __restrict__ pk1, const u64* __restrict__ pk2,
                        const float* __restrict__ d3h,
                        unsigned* __restrict__ bestidx, u64* __restrict__ bestkey,
                        int* __restrict__ wlist, int* __restrict__ wcount,
                        int* __restrict__ slist, int* __restrict__ s2list,
                        int* __restrict__ scount) {
  const int r = blockIdx.x * 256 + threadIdx.x;
  const int lane = threadIdx.x & 63;
  const u64 k1a = pk1[r], k1b = pk1[NROWS + r];
  const u64 k2a = pk2[r], k2b = pk2[NROWS + r];
  const float d3a = d3h[r], d3b = d3h[NROWS + r];
  const u64 K1 = umin64(k1a, k1b);
  const u64 K2 = umin64(umax64(k1a, k1b), umin64(k2a, k2b));
  const float d3 = fminf(fminf(d3a, d3b),
                         fminf(dkey(umax64(k1a, k2b)), dkey(umax64(k2a, k1b))));
  const float d1 = dkey(K1);
  const float d2 = dkey(K2);
  const unsigned i1x = (unsigned)(K1 & 0xffffffffull);
  const unsigned i2x = (unsigned)(K2 & 0xffffffffull);
  const bool amb = (d2 - d1) < MARGIN;
  const bool hard = ((d3 - d1) < MARGIN) || (amb && i2x == 0xffffffffu);
  const bool soft = amb && !hard;
  bestidx[r] = i1x | (hard ? 0x80000000u : 0u);
  if (hard) bestkey[r] = ~0ull;
  {
    const u64 mb = __ballot(hard);
    const int cnt = __popcll(mb);
    int base = 0;
    if (lane == 0 && cnt) base = atomicAdd(wcount, cnt);
    base = __shfl(base, 0);
    if (hard) wlist[base + __popcll(mb & ((1ull << lane) - 1ull))] = r;
  }
  {
    const u64 mb = __ballot(soft);
    const int cnt = __popcll(mb);
    int base = 0;
    if (lane == 0 && cnt) base = atomicAdd(scount, cnt);
    base = __shfl(base, 0);
    if (soft) {
      const int slot = base + __popcll(mb & ((1ull << lane) - 1ull));
      slist[slot] = r;
      s2list[slot] = (int)i2x;
    }
  }
}

// ---------------------------------------------------------------------------
// K4a: soft rows — exact 2-candidate compare. One wave per row.
// ---------------------------------------------------------------------------
__launch_bounds__(256)
__global__ void k_soft(const float* __restrict__ x, const float* __restrict__ cb,
                       const int* __restrict__ slist, const int* __restrict__ s2list,
                       const int* __restrict__ scount, unsigned* __restrict__ bestidx) {
  const int tid = threadIdx.x;
  const int lane = tid & 63;
  const int gw = blockIdx.x * 4 + (tid >> 6);
  const int ns = *scount;
  for (int i = gw; i < ns; i += 256) {
    const int r = slist[i];
    const unsigned c1 = bestidx[r] & 0x7fffffffu;
    const unsigned c2 = (unsigned)s2list[i];
    const float4 xv = *((const float4*)(x + (size_t)r * DIMS) + lane);
    const float4 a = *((const float4*)(cb + (size_t)c1 * DIMS) + lane);
    const float4 b = *((const float4*)(cb + (size_t)c2 * DIMS) + lane);
    float e, p1, p2;
    e = xv.x - a.x; p1 = e * e;
    e = xv.y - a.y; p1 = fmaf(e, e, p1);
    e = xv.z - a.z; p1 = fmaf(e, e, p1);
    e = xv.w - a.w; p1 = fmaf(e, e, p1);
    e = xv.x - b.x; p2 = e * e;
    e = xv.y - b.y; p2 = fmaf(e, e, p2);
    e = xv.z - b.z; p2 = fmaf(e, e, p2);
    e = xv.w - b.w; p2 = fmaf(e, e, p2);
    double s1 = (double)p1, s2 = (double)p2;
#pragma unroll
    for (int mk = 1; mk < 64; mk <<= 1) {
      s1 += __shfl_xor(s1, mk);
      s2 += __shfl_xor(s2, mk);
    }
    unsigned win = (s1 < s2) ? c1 : ((s2 < s1) ? c2 : min(c1, c2));
    if (lane == 0) bestidx[r] = win;
  }
}

// ---------------------------------------------------------------------------
// K4b: hard rows — full exact scan (codes in regs, rows via dbuf LDS).
// ---------------------------------------------------------------------------
__launch_bounds__(512, 1)
__global__ void k_refine3(const float* __restrict__ x, const float* __restrict__ cb,
                          const int* __restrict__ wlist, const int* __restrict__ wcount,
                          u64* __restrict__ bestkey) {
  __shared__ float xl[2][8][272];
  __shared__ int rl[2][8];
  const int tid = threadIdx.x;
  const int lane = tid & 63;
  const int ci = tid >> 4;
  const int piece = tid & 15;
  const int codeg = blockIdx.x * 32 + ci;

  float cr[16];
  {
    const float4* cp = (const float4*)(cb + (size_t)codeg * DIMS + piece * 16);
#pragma unroll
    for (int i = 0; i < 4; ++i) {
      const float4 v = cp[i];
      cr[i * 4 + 0] = v.x; cr[i * 4 + 1] = v.y;
      cr[i * 4 + 2] = v.z; cr[i * 4 + 3] = v.w;
    }
  }

  const int nf = *wcount;
  if (nf == 0) return;
  const int nc = (nf + 7) >> 3;
  const int startc = (int)(((long long)blockIdx.x * nc) >> 8);

  const int slot = tid >> 6;
  const int dlane = tid & 63;

  auto stage = [&](int c, int buf) {
    int chunkid = startc + c;
    if (chunkid >= nc) chunkid -= nc;
    int ridx = chunkid * 8 + slot;
    if (ridx >= nf) ridx %= nf;
    const int row = wlist[ridx];
    if (dlane == 0) rl[buf][slot] = row;
    const float4* xs = (const float4*)(x + (size_t)row * DIMS) + dlane;
    *(float4*)&xl[buf][slot][dlane * 4] = *xs;
  };

  stage(0, 0);
#pragma unroll 1
  for (int c = 0; c < nc; ++c) {
    const int buf = c & 1;
    __syncthreads();
    if (c + 1 < nc) stage(c + 1, buf ^ 1);

    u64 k[8];
#pragma unroll
    for (int r = 0; r < 8; ++r) {
      const float* xr = &xl[buf][r][piece * 16];
      const float4 a0 = *(const float4*)(xr + 0);
      const float4 a1 = *(const float4*)(xr + 4);
      const float4 a2 = *(const float4*)(xr + 8);
      const float4 a3 = *(const float4*)(xr + 12);
      float s0, s1, s2, s3;
      {
        float d;
        d = a0.x - cr[0];  s0 = d * d;
        d = a0.y - cr[1];  s0 = fmaf(d, d, s0);
        d = a0.z - cr[2];  s0 = fmaf(d, d, s0);
        d = a0.w - cr[3];  s0 = fmaf(d, d, s0);
        d = a1.x - cr[4];  s1 = d * d;
        d = a1.y - cr[5];  s1 = fmaf(d, d, s1);
        d = a1.z - cr[6];  s1 = fmaf(d, d, s1);
        d = a1.w - cr[7];  s1 = fmaf(d, d, s1);
        d = a2.x - cr[8];  s2 = d * d;
        d = a2.y - cr[9];  s2 = fmaf(d, d, s2);
        d = a2.z - cr[10]; s2 = fmaf(d, d, s2);
        d = a2.w - cr[11]; s2 = fmaf(d, d, s2);
        d = a3.x - cr[12]; s3 = d * d;
        d = a3.y - cr[13]; s3 = fmaf(d, d, s3);
        d = a3.z - cr[14]; s3 = fmaf(d, d, s3);
        d = a3.w - cr[15]; s3 = fmaf(d, d, s3);
      }
      float s = (s0 + s1) + (s2 + s3);
      s += __shfl_xor(s, 1);
      s += __shfl_xor(s, 2);
      s += __shfl_xor(s, 4);
      s += __shfl_xor(s, 8);
      u64 key = ((u64)__float_as_uint(s) << 32) | (unsigned)codeg;
      u64 ok = __shfl_xor(key, 16);
      key = umin64(key, ok);
      ok = __shfl_xor(key, 32);
      key = umin64(key, ok);
      k[r] = key;
    }

    if (lane == 0) {
      int rows[8];
      u64 cur[8];
#pragma unroll
      for (int r = 0; r < 8; ++r) rows[r] = rl[buf][r];
#pragma unroll
      for (int r = 0; r < 8; ++r) cur[r] = bestkey[rows[r]];
#pragma unroll
      for (int r = 0; r < 8; ++r)
        if (k[r] < cur[r]) atomicMin(&bestkey[rows[r]], k[r]);
    }
  }
}

// ---------------------------------------------------------------------------
// K5: gather quantized output + per-block loss partials (no global atomics).
// ---------------------------------------------------------------------------
__launch_bounds__(256)
__global__ void k_out2(const float* __restrict__ x, const float* __restrict__ cb,
                       const unsigned* __restrict__ bestidx,
                       const u64* __restrict__ bestkey,
                       float* __restrict__ out, float* __restrict__ partials) {
  __shared__ float wsum[4];
  float s = 0.f;
#pragma unroll
  for (int it = 0; it < 4; ++it) {
    const int gid = (it * 2048 + blockIdx.x) * 256 + threadIdx.x;
    const int row = gid >> 6, d4 = gid & 63;
    const unsigned bi = bestidx[row];
    unsigned idx = bi & 0x7fffffffu;
    if (bi >> 31) idx = (unsigned)(bestkey[row] & 0xffffffffull);
    const float4 q = *(const float4*)(cb + (size_t)idx * DIMS + d4 * 4);
    const float4 xv = *(const float4*)(x + (size_t)gid * 4);
    *(float4*)(out + (size_t)gid * 4) = q;
    const float dx = q.x - xv.x, dy = q.y - xv.y, dz = q.z - xv.z, dw = q.w - xv.w;
    s += dx * dx + dy * dy + dz * dz + dw * dw;
  }
#pragma unroll
  for (int m = 1; m < 64; m <<= 1) s += __shfl_xor(s, m);
  if ((threadIdx.x & 63) == 0) wsum[threadIdx.x >> 6] = s;
  __syncthreads();
  if (threadIdx.x == 0)
    partials[blockIdx.x] = wsum[0] + wsum[1] + wsum[2] + wsum[3];
}

// ---------------------------------------------------------------------------
// K6: final loss reduce.
// ---------------------------------------------------------------------------
__global__ void k_loss(const float* __restrict__ partials, float* __restrict__ loss_cell) {
  __shared__ double wsum[4];
  double s = 0.0;
#pragma unroll
  for (int i = 0; i < 8; ++i) s += (double)partials[i * 256 + threadIdx.x];
#pragma unroll
  for (int m = 1; m < 64; m <<= 1) s += __shfl_xor(s, m);
  if ((threadIdx.x & 63) == 0) wsum[threadIdx.x >> 6] = s;
  __syncthreads();
  if (threadIdx.x == 0)
    *loss_cell = (float)((wsum[0] + wsum[1] + wsum[2] + wsum[3]) *
                         (1.25 / (double)((size_t)NROWS * DIMS)));
}

// ---------------------------------------------------------------------------
extern "C" void kernel_launch(void* const* d_in, const int* in_sizes, int n_in,
                              void* d_out, int out_size, void* d_ws, size_t ws_size,
                              hipStream_t stream) {
  const float* x = (const float*)d_in[0];
  const float* cb = (const float*)d_in[1];
  float* out = (float*)d_out;
  char* ws = (char*)d_ws;

  float* cnorm = (float*)(ws + 0);                //  32 KB
  u64* pk1 = (u64*)(ws + 32768);                  // 512 KB [NH][NROWS]
  u64* pk2 = (u64*)(ws + 557056);                 // 512 KB
  float* d3h = (float*)(ws + 1081344);            // 256 KB
  unsigned* bestidx = (unsigned*)(ws + 1343488);  // 128 KB
  u64* bestkey = (u64*)(ws + 1474560);            // 256 KB
  int* wlist = (int*)(ws + 1736704);              // 128 KB
  int* slist = (int*)(ws + 1867776);              // 128 KB
  int* s2list = (int*)(ws + 1998848);             // 128 KB
  int* wcount = (int*)(ws + 2129920);
  int* scount = wcount + 1;
  float* partials = (float*)(ws + 2129984);       //   8 KB
  _Float16* cbh = (_Float16*)(ws + 2138176);      //   4 MB (fast path)
  float* loss_cell = out + (NROWS * DIMS);

  const bool fast = ws_size >= (size_t)(2138176 + KCODES * DIMS * 2);

  if (fast) {
    k_prep2<<<KCODES / 4, 256, 0, stream>>>(cb, cbh, cnorm, wcount, scount, loss_cell);
    k_gemm2<<<(NROWS / 256) * NH, 512, 0, stream>>>(x, cbh, cnorm, pk1, pk2, d3h);
  } else {
    k_cnorm<<<KCODES / 4, 256, 0, stream>>>(cb, cnorm, wcount, scount, loss_cell);
    k_gemm_fb<<<(NROWS / 256) * NH, 512, 0, stream>>>(x, cb, cnorm, pk1, pk2, d3h);
  }
  k_merge<<<NROWS / 256, 256, 0, stream>>>(pk1, pk2, d3h, bestidx, bestkey,
                                           wlist, wcount, slist, s2list, scount);
  k_soft<<<64, 256, 0, stream>>>(x, cb, slist, s2list, scount, bestidx);
  k_refine3<<<KCODES / 32, 512, 0, stream>>>(x, cb, wlist, wcount, bestkey);
  k_out2<<<2048, 256, 0, stream>>>(x, cb, bestidx, bestkey, out, partials);
  k_loss<<<1, 256, 0, stream>>>(partials, loss_cell);
}

// Round 15
// 223.403 us; speedup vs baseline: 1.0396x; 1.0396x over previous
//
#include <hip/hip_runtime.h>
#include <hip/hip_fp16.h>

#define NROWS 32768
#define DIMS 256
#define KCODES 8192
#define NH 2            // K-halves (grid = 128 rowblks x 2 halves = 256 blocks)
#define HCODES 4096
#define MARGIN 0.10f

typedef _Float16 half8 __attribute__((ext_vector_type(8)));
typedef _Float16 half4 __attribute__((ext_vector_type(4)));
typedef float f32x4 __attribute__((ext_vector_type(4)));
typedef unsigned long long u64;

__device__ __forceinline__ void gload_lds16(const void* g, void* l) {
  __builtin_amdgcn_global_load_lds((const __attribute__((address_space(1))) unsigned int*)g,
                                   (__attribute__((address_space(3))) unsigned int*)l, 16, 0, 0);
}

__device__ __forceinline__ unsigned sortable_f32(float f) {
  unsigned u = __float_as_uint(f);
  return u ^ (unsigned)(((int)u >> 31) | 0x80000000);
}
__device__ __forceinline__ float unsortable_f32(unsigned s) {
  const unsigned m = ((int)s < 0) ? 0x80000000u : 0xFFFFFFFFu;
  return __uint_as_float(s ^ m);
}
__device__ __forceinline__ u64 umin64(u64 a, u64 b) { return a < b ? a : b; }
__device__ __forceinline__ u64 umax64(u64 a, u64 b) { return a > b ? a : b; }
__device__ __forceinline__ float dkey(u64 k) { return unsortable_f32((unsigned)(k >> 32)); }

// ---------------------------------------------------------------------------
// K0 (fused, r14-verified): cb -> f16 codebook + squared norms + zero
// counters, one pass. 2048 blocks x 256 thr; one wave per code.
// ---------------------------------------------------------------------------
__global__ void k_prep2(const float* __restrict__ cb, _Float16* __restrict__ cbh,
                        float* __restrict__ cnorm, int* __restrict__ wcount,
                        int* __restrict__ scount, float* __restrict__ loss_cell) {
  const int lane = threadIdx.x & 63;
  const int code = blockIdx.x * 4 + (threadIdx.x >> 6);
  const float4 v = *((const float4*)(cb + (size_t)code * DIMS) + lane);
  half4 h;
  h[0] = (_Float16)v.x; h[1] = (_Float16)v.y;
  h[2] = (_Float16)v.z; h[3] = (_Float16)v.w;
  *((half4*)(cbh + (size_t)code * DIMS) + lane) = h;
  float s = v.x * v.x + v.y * v.y + v.z * v.z + v.w * v.w;
#pragma unroll
  for (int m = 1; m < 64; m <<= 1) s += __shfl_xor(s, m);
  if (lane == 0) cnorm[code] = s;
  if (blockIdx.x == 0 && threadIdx.x == 0) {
    *wcount = 0; *scount = 0; *loss_cell = 0.0f;
  }
}

// ---------------------------------------------------------------------------
// K1 (fallback path only): norms + zero counters.
// ---------------------------------------------------------------------------
__global__ void k_cnorm(const float* __restrict__ cb, float* __restrict__ cnorm,
                        int* __restrict__ wcount, int* __restrict__ scount,
                        float* __restrict__ loss_cell) {
  const int lane = threadIdx.x & 63;
  const int code = blockIdx.x * 4 + (threadIdx.x >> 6);
  const float4 v = *((const float4*)(cb + code * DIMS) + lane);
  float s = v.x * v.x + v.y * v.y + v.z * v.z + v.w * v.w;
#pragma unroll
  for (int m = 1; m < 64; m <<= 1) s += __shfl_xor(s, m);
  if (lane == 0) cnorm[code] = s;
  if (blockIdx.x == 0 && threadIdx.x == 0) {
    *wcount = 0; *scount = 0; *loss_cell = 0.0f;
  }
}

// ---------------------------------------------------------------------------
// K2 (fast): THE MEASURED-BEST GEMM (r9/r13 bench: 158 us, MfmaUtil 40.3%).
// Half-split grid 256, 512 thr, M_rep=2, 64-code tiles, swizzled dbuf LDS
// via global_load_lds, slim 4-op/value epilogue, once-per-row 3-key
// sentinel butterfly (exact d2-with-index + d3).
// Ledger vs this structure: M_rep=4 (-13%), acc-pipe (-17%), counted-vmcnt
// (RACED), 2 blocks/CU (null), 128-code tiles (-9%). Do not touch.
// ---------------------------------------------------------------------------
__launch_bounds__(512)
__global__ void k_gemm2(const float* __restrict__ x, const _Float16* __restrict__ cbh,
                        const float* __restrict__ cnorm,
                        u64* __restrict__ pk1, u64* __restrict__ pk2,
                        float* __restrict__ d3h) {
  __shared__ char B[2][32768];
  const int tid = threadIdx.x;
  const int lane = tid & 63;
  const int w = tid >> 6;
  const int l15 = lane & 15;
  const int lh = lane >> 4;
  const int rowblk = (int)blockIdx.x >> 1;
  const int half = (int)blockIdx.x & 1;
  const int row0 = rowblk * 256 + w * 32;
  const char* cbh_half = (const char*)(cbh + (size_t)half * HCODES * DIMS);

  half8 a[2][8];
#pragma unroll
  for (int m = 0; m < 2; ++m) {
#pragma unroll
    for (int kf = 0; kf < 8; ++kf) {
      const float* s = x + (size_t)(row0 + m * 16 + l15) * DIMS + kf * 32 + lh * 8;
      const float4 v0 = *(const float4*)s;
      const float4 v1 = *(const float4*)(s + 4);
      half8 h;
      h[0] = (_Float16)v0.x; h[1] = (_Float16)v0.y;
      h[2] = (_Float16)v0.z; h[3] = (_Float16)v0.w;
      h[4] = (_Float16)v1.x; h[5] = (_Float16)v1.y;
      h[6] = (_Float16)v1.z; h[7] = (_Float16)v1.w;
      a[m][kf] = h;
    }
  }

  int srcoff[4];
#pragma unroll
  for (int i = 0; i < 4; ++i) {
    const int L = i * 512 + tid;
    const int hi = L >> 6;
    const int lhL = hi & 3, chL = hi >> 2;
    const int code = (L & 63) ^ ((lhL & 1) << 4);
    srcoff[i] = code * 512 + chL * 64 + lhL * 16;
  }

  const int lanebase = l15 * 16 + lh * 1024;
  const int bs = (lh & 1) << 8;
  const int lbp = lanebase + bs;
  const int lbm = lanebase - bs;

  float r1[2][4], r2[2][4];
  int i1[2][4];
#pragma unroll
  for (int m = 0; m < 2; ++m)
#pragma unroll
    for (int j = 0; j < 4; ++j) { r1[m][j] = 3.0e38f; r2[m][j] = 3.0e38f; i1[m][j] = 0; }

  char* lds = &B[0][0];

  auto stage = [&](int t, int bufoff) {
#pragma unroll
    for (int i = 0; i < 4; ++i)
      gload_lds16(cbh_half + t * 32768 + srcoff[i],
                  lds + bufoff + (i * 512 + w * 64) * 16);
  };

  auto compute_tile = [&](int t, int bufoff) {
    const int cbase = half * HCODES + t * 64;
    float cn[4];
#pragma unroll
    for (int n = 0; n < 4; ++n) cn[n] = cnorm[cbase + n * 16 + l15];
    f32x4 acc[2][4];
#pragma unroll
    for (int m = 0; m < 2; ++m)
#pragma unroll
      for (int n = 0; n < 4; ++n) acc[m][n] = (f32x4){0.f, 0.f, 0.f, 0.f};
#pragma unroll
    for (int ch = 0; ch < 8; ++ch) {
      half8 b[4];
#pragma unroll
      for (int n = 0; n < 4; ++n) {
        const int ad = ((n & 1) ? lbm : lbp) + bufoff + ch * 4096 + n * 256;
        b[n] = *(const half8*)(lds + ad);
      }
#pragma unroll
      for (int m = 0; m < 2; ++m)
#pragma unroll
        for (int n = 0; n < 4; ++n)
          acc[m][n] = __builtin_amdgcn_mfma_f32_16x16x32_f16(a[m][ch], b[n], acc[m][n], 0, 0, 0);
    }
#pragma unroll
    for (int m = 0; m < 2; ++m)
#pragma unroll
      for (int n = 0; n < 4; ++n) {
        const int ic = t * 4 + n;
#pragma unroll
        for (int j = 0; j < 4; ++j) {
          const float d = fmaf(-2.0f, acc[m][n][j], cn[n]);
          const bool lt1 = d < r1[m][j];
          r2[m][j] = __builtin_amdgcn_fmed3f(d, r1[m][j], r2[m][j]);
          i1[m][j] = lt1 ? ic : i1[m][j];
          r1[m][j] = fminf(d, r1[m][j]);
        }
      }
  };

  stage(0, 0);
#pragma unroll 1
  for (int t = 0; t < 64; t += 2) {
    __syncthreads();
    if (t + 1 < 64) stage(t + 1, 32768);
    compute_tile(t, 0);
    __syncthreads();
    if (t + 2 < 64) stage(t + 2, 0);
    compute_tile(t + 1, 32768);
  }

  // 3-key butterfly: k1=(val,idx), k2=(val,SENTINEL), k3=INF.
#pragma unroll
  for (int m = 0; m < 2; ++m)
#pragma unroll
    for (int j = 0; j < 4; ++j) {
      const int ia = i1[m][j];
      const unsigned c1 = half * HCODES + (ia >> 2) * 64 + (ia & 3) * 16 + l15;
      u64 k1 = ((u64)sortable_f32(r1[m][j]) << 32) | c1;
      u64 k2 = ((u64)sortable_f32(r2[m][j]) << 32) | 0xffffffffu;
      u64 k3 = ~0ull;
#pragma unroll
      for (int mk = 1; mk < 16; mk <<= 1) {
        const u64 o1 = __shfl_xor(k1, mk);
        const u64 o2 = __shfl_xor(k2, mk);
        const u64 o3 = __shfl_xor(k3, mk);
        const u64 hi1 = umax64(k1, o1);
        k3 = umin64(umin64(k3, o3), umin64(umax64(k1, o2), umax64(k2, o1)));
        k2 = umin64(hi1, umin64(k2, o2));
        k1 = umin64(k1, o1);
      }
      if (l15 == 0) {
        const int rg = row0 + m * 16 + lh * 4 + j;
        pk1[half * NROWS + rg] = k1;
        pk2[half * NROWS + rg] = k2;
        d3h[half * NROWS + rg] = dkey(k3);
      }
    }
}

// ---------------------------------------------------------------------------
// K2 (fallback, ws too small): in-kernel convert, padded LDS, same outputs.
// ---------------------------------------------------------------------------
__launch_bounds__(512)
__global__ void k_gemm_fb(const float* __restrict__ x, const float* __restrict__ cb,
                          const float* __restrict__ cnorm,
                          u64* __restrict__ pk1, u64* __restrict__ pk2,
                          float* __restrict__ d3h) {
  __shared__ _Float16 clds[128][40];
  const int tid = threadIdx.x;
  const int lane = tid & 63;
  const int w = tid >> 6;
  const int l15 = lane & 15;
  const int lh = lane >> 4;
  const int rowblk = (int)blockIdx.x >> 1;
  const int half = (int)blockIdx.x & 1;
  const int row0 = rowblk * 256 + w * 32;

  half8 a[2][8];
#pragma unroll
  for (int m = 0; m < 2; ++m) {
#pragma unroll
    for (int kf = 0; kf < 8; ++kf) {
      const float* s = x + (row0 + m * 16 + l15) * DIMS + kf * 32 + lh * 8;
      const float4 v0 = *(const float4*)s;
      const float4 v1 = *(const float4*)(s + 4);
      half8 h;
      h[0] = (_Float16)v0.x; h[1] = (_Float16)v0.y;
      h[2] = (_Float16)v0.z; h[3] = (_Float16)v0.w;
      h[4] = (_Float16)v1.x; h[5] = (_Float16)v1.y;
      h[6] = (_Float16)v1.z; h[7] = (_Float16)v1.w;
      a[m][kf] = h;
    }
  }

  float r1[2][4], r2[2][4];
  int i1[2][4];
#pragma unroll
  for (int m = 0; m < 2; ++m)
#pragma unroll
    for (int j = 0; j < 4; ++j) { r1[m][j] = 3.0e38f; r2[m][j] = 3.0e38f; i1[m][j] = 0; }

  const int stg_code = tid >> 2;
  const int stg_seg = tid & 3;

  for (int ct = 0; ct < 32; ++ct) {
    const int cbase = half * HCODES + ct * 128;
    f32x4 acc[2][8];
#pragma unroll
    for (int m = 0; m < 2; ++m)
#pragma unroll
      for (int n = 0; n < 8; ++n) acc[m][n] = (f32x4){0.f, 0.f, 0.f, 0.f};

#pragma unroll
    for (int ch = 0; ch < 8; ++ch) {
      __syncthreads();
      {
        const float* s = cb + (cbase + stg_code) * DIMS + ch * 32 + stg_seg * 8;
        const float4 v0 = *(const float4*)s;
        const float4 v1 = *(const float4*)(s + 4);
        half8 h;
        h[0] = (_Float16)v0.x; h[1] = (_Float16)v0.y;
        h[2] = (_Float16)v0.z; h[3] = (_Float16)v0.w;
        h[4] = (_Float16)v1.x; h[5] = (_Float16)v1.y;
        h[6] = (_Float16)v1.z; h[7] = (_Float16)v1.w;
        *(half8*)&clds[stg_code][stg_seg * 8] = h;
      }
      __syncthreads();
      half8 b[8];
#pragma unroll
      for (int n = 0; n < 8; ++n)
        b[n] = *(const half8*)&clds[n * 16 + l15][lh * 8];
#pragma unroll
      for (int m = 0; m < 2; ++m)
#pragma unroll
        for (int n = 0; n < 8; ++n)
          acc[m][n] = __builtin_amdgcn_mfma_f32_16x16x32_f16(a[m][ch], b[n], acc[m][n], 0, 0, 0);
    }

    float cn[8];
#pragma unroll
    for (int n = 0; n < 8; ++n) cn[n] = cnorm[cbase + n * 16 + l15];
#pragma unroll
    for (int m = 0; m < 2; ++m)
#pragma unroll
      for (int n = 0; n < 8; ++n) {
        const int ic = ct * 8 + n;
#pragma unroll
        for (int j = 0; j < 4; ++j) {
          const float d = fmaf(-2.0f, acc[m][n][j], cn[n]);
          const bool lt1 = d < r1[m][j];
          r2[m][j] = __builtin_amdgcn_fmed3f(d, r1[m][j], r2[m][j]);
          i1[m][j] = lt1 ? ic : i1[m][j];
          r1[m][j] = fminf(d, r1[m][j]);
        }
      }
  }

#pragma unroll
  for (int m = 0; m < 2; ++m)
#pragma unroll
    for (int j = 0; j < 4; ++j) {
      const int ia = i1[m][j];
      const unsigned c1 = half * HCODES + (ia >> 3) * 128 + (ia & 7) * 16 + l15;
      u64 k1 = ((u64)sortable_f32(r1[m][j]) << 32) | c1;
      u64 k2 = ((u64)sortable_f32(r2[m][j]) << 32) | 0xffffffffu;
      u64 k3 = ~0ull;
#pragma unroll
      for (int mk = 1; mk < 16; mk <<= 1) {
        const u64 o1 = __shfl_xor(k1, mk);
        const u64 o2 = __shfl_xor(k2, mk);
        const u64 o3 = __shfl_xor(k3, mk);
        const u64 hi1 = umax64(k1, o1);
        k3 = umin64(umin64(k3, o3), umin64(umax64(k1, o2), umax64(k2, o1)));
        k2 = umin64(hi1, umin64(k2, o2));
        k1 = umin64(k1, o1);
      }
      if (l15 == 0) {
        const int rg = row0 + m * 16 + lh * 4 + j;
        pk1[half * NROWS + rg] = k1;
        pk2[half * NROWS + rg] = k2;
        d3h[half * NROWS + rg] = dkey(k3);
      }
    }
}

// ---------------------------------------------------------------------------
// K3: fold halves; classify clean / soft (2-candidate) / hard (full scan).
// hard = 3-way tie (d3) OR ambiguous-without-idx2 (sentinel collision).
// ---------------------------------------------------------------------------
__global__ void k_merge(const u64* __restrict__ pk1, const u64* __restrict__ pk2,
                        const float* __restrict__ d3h,
                        unsigned* __restrict__ bestidx, u64* __restrict__ bestkey,
                        int* __restrict__ wlist, int* __restrict__ wcount,
                        int* __restrict__ slist, int* __restrict__ s2list,
                        int* __restrict__ scount) {
  const int r = blockIdx.x * 256 + threadIdx.x;
  const int lane = threadIdx.x & 63;
  const u64 k1a = pk1[r], k1b = pk1[NROWS + r];
  const u64 k2a = pk2[r], k2b = pk2[NROWS + r];
  const float d3a = d3h[r], d3b = d3h[NROWS + r];
  const u64 K1 = umin64(k1a, k1b);
  const u64 K2 = umin64(umax64(k1a, k1b), umin64(k2a, k2b));
  const float d3 = fminf(fminf(d3a, d3b),
                         fminf(dkey(umax64(k1a, k2b)), dkey(umax64(k2a, k1b))));
  const float d1 = dkey(K1);
  const float d2 = dkey(K2);
  const unsigned i1x = (unsigned)(K1 & 0xffffffffull);
  const unsigned i2x = (unsigned)(K2 & 0xffffffffull);
  const bool amb = (d2 - d1) < MARGIN;
  const bool hard = ((d3 - d1) < MARGIN) || (amb && i2x == 0xffffffffu);
  const bool soft = amb && !hard;
  bestidx[r] = i1x | (hard ? 0x80000000u : 0u);
  if (hard) bestkey[r] = ~0ull;
  {
    const u64 mb = __ballot(hard);
    const int cnt = __popcll(mb);
    int base = 0;
    if (lane == 0 && cnt) base = atomicAdd(wcount, cnt);
    base = __shfl(base, 0);
    if (hard) wlist[base + __popcll(mb & ((1ull << lane) - 1ull))] = r;
  }
  {
    const u64 mb = __ballot(soft);
    const int cnt = __popcll(mb);
    int base = 0;
    if (lane == 0 && cnt) base = atomicAdd(scount, cnt);
    base = __shfl(base, 0);
    if (soft) {
      const int slot = base + __popcll(mb & ((1ull << lane) - 1ull));
      slist[slot] = r;
      s2list[slot] = (int)i2x;
    }
  }
}

// ---------------------------------------------------------------------------
// K4a: soft rows — exact 2-candidate compare. One wave per row.
// ---------------------------------------------------------------------------
__launch_bounds__(256)
__global__ void k_soft(const float* __restrict__ x, const float* __restrict__ cb,
                       const int* __restrict__ slist, const int* __restrict__ s2list,
                       const int* __restrict__ scount, unsigned* __restrict__ bestidx) {
  const int tid = threadIdx.x;
  const int lane = tid & 63;
  const int gw = blockIdx.x * 4 + (tid >> 6);
  const int ns = *scount;
  for (int i = gw; i < ns; i += 256) {
    const int r = slist[i];
    const unsigned c1 = bestidx[r] & 0x7fffffffu;
    const unsigned c2 = (unsigned)s2list[i];
    const float4 xv = *((const float4*)(x + (size_t)r * DIMS) + lane);
    const float4 a = *((const float4*)(cb + (size_t)c1 * DIMS) + lane);
    const float4 b = *((const float4*)(cb + (size_t)c2 * DIMS) + lane);
    float e, p1, p2;
    e = xv.x - a.x; p1 = e * e;
    e = xv.y - a.y; p1 = fmaf(e, e, p1);
    e = xv.z - a.z; p1 = fmaf(e, e, p1);
    e = xv.w - a.w; p1 = fmaf(e, e, p1);
    e = xv.x - b.x; p2 = e * e;
    e = xv.y - b.y; p2 = fmaf(e, e, p2);
    e = xv.z - b.z; p2 = fmaf(e, e, p2);
    e = xv.w - b.w; p2 = fmaf(e, e, p2);
    double s1 = (double)p1, s2 = (double)p2;
#pragma unroll
    for (int mk = 1; mk < 64; mk <<= 1) {
      s1 += __shfl_xor(s1, mk);
      s2 += __shfl_xor(s2, mk);
    }
    unsigned win = (s1 < s2) ? c1 : ((s2 < s1) ? c2 : min(c1, c2));
    if (lane == 0) bestidx[r] = win;
  }
}

// ---------------------------------------------------------------------------
// K4b: hard rows — full exact scan (codes in regs, rows via dbuf LDS).
// ---------------------------------------------------------------------------
__launch_bounds__(512, 1)
__global__ void k_refine3(const float* __restrict__ x, const float* __restrict__ cb,
                          const int* __restrict__ wlist, const int* __restrict__ wcount,
                          u64* __restrict__ bestkey) {
  __shared__ float xl[2][8][272];
  __shared__ int rl[2][8];
  const int tid = threadIdx.x;
  const int lane = tid & 63;
  const int ci = tid >> 4;
  const int piece = tid & 15;
  const int codeg = blockIdx.x * 32 + ci;

  float cr[16];
  {
    const float4* cp = (const float4*)(cb + (size_t)codeg * DIMS + piece * 16);
#pragma unroll
    for (int i = 0; i < 4; ++i) {
      const float4 v = cp[i];
      cr[i * 4 + 0] = v.x; cr[i * 4 + 1] = v.y;
      cr[i * 4 + 2] = v.z; cr[i * 4 + 3] = v.w;
    }
  }

  const int nf = *wcount;
  if (nf == 0) return;
  const int nc = (nf + 7) >> 3;
  const int startc = (int)(((long long)blockIdx.x * nc) >> 8);

  const int slot = tid >> 6;
  const int dlane = tid & 63;

  auto stage = [&](int c, int buf) {
    int chunkid = startc + c;
    if (chunkid >= nc) chunkid -= nc;
    int ridx = chunkid * 8 + slot;
    if (ridx >= nf) ridx %= nf;
    const int row = wlist[ridx];
    if (dlane == 0) rl[buf][slot] = row;
    const float4* xs = (const float4*)(x + (size_t)row * DIMS) + dlane;
    *(float4*)&xl[buf][slot][dlane * 4] = *xs;
  };

  stage(0, 0);
#pragma unroll 1
  for (int c = 0; c < nc; ++c) {
    const int buf = c & 1;
    __syncthreads();
    if (c + 1 < nc) stage(c + 1, buf ^ 1);

    u64 k[8];
#pragma unroll
    for (int r = 0; r < 8; ++r) {
      const float* xr = &xl[buf][r][piece * 16];
      const float4 a0 = *(const float4*)(xr + 0);
      const float4 a1 = *(const float4*)(xr + 4);
      const float4 a2 = *(const float4*)(xr + 8);
      const float4 a3 = *(const float4*)(xr + 12);
      float s0, s1, s2, s3;
      {
        float d;
        d = a0.x - cr[0];  s0 = d * d;
        d = a0.y - cr[1];  s0 = fmaf(d, d, s0);
        d = a0.z - cr[2];  s0 = fmaf(d, d, s0);
        d = a0.w - cr[3];  s0 = fmaf(d, d, s0);
        d = a1.x - cr[4];  s1 = d * d;
        d = a1.y - cr[5];  s1 = fmaf(d, d, s1);
        d = a1.z - cr[6];  s1 = fmaf(d, d, s1);
        d = a1.w - cr[7];  s1 = fmaf(d, d, s1);
        d = a2.x - cr[8];  s2 = d * d;
        d = a2.y - cr[9];  s2 = fmaf(d, d, s2);
        d = a2.z - cr[10]; s2 = fmaf(d, d, s2);
        d = a2.w - cr[11]; s2 = fmaf(d, d, s2);
        d = a3.x - cr[12]; s3 = d * d;
        d = a3.y - cr[13]; s3 = fmaf(d, d, s3);
        d = a3.z - cr[14]; s3 = fmaf(d, d, s3);
        d = a3.w - cr[15]; s3 = fmaf(d, d, s3);
      }
      float s = (s0 + s1) + (s2 + s3);
      s += __shfl_xor(s, 1);
      s += __shfl_xor(s, 2);
      s += __shfl_xor(s, 4);
      s += __shfl_xor(s, 8);
      u64 key = ((u64)__float_as_uint(s) << 32) | (unsigned)codeg;
      u64 ok = __shfl_xor(key, 16);
      key = umin64(key, ok);
      ok = __shfl_xor(key, 32);
      key = umin64(key, ok);
      k[r] = key;
    }

    if (lane == 0) {
      int rows[8];
      u64 cur[8];
#pragma unroll
      for (int r = 0; r < 8; ++r) rows[r] = rl[buf][r];
#pragma unroll
      for (int r = 0; r < 8; ++r) cur[r] = bestkey[rows[r]];
#pragma unroll
      for (int r = 0; r < 8; ++r)
        if (k[r] < cur[r]) atomicMin(&bestkey[rows[r]], k[r]);
    }
  }
}

// ---------------------------------------------------------------------------
// K5: gather quantized output + per-block loss partials (no global atomics).
// ---------------------------------------------------------------------------
__launch_bounds__(256)
__global__ void k_out2(const float* __restrict__ x, const float* __restrict__ cb,
                       const unsigned* __restrict__ bestidx,
                       const u64* __restrict__ bestkey,
                       float* __restrict__ out, float* __restrict__ partials) {
  __shared__ float wsum[4];
  float s = 0.f;
#pragma unroll
  for (int it = 0; it < 4; ++it) {
    const int gid = (it * 2048 + blockIdx.x) * 256 + threadIdx.x;
    const int row = gid >> 6, d4 = gid & 63;
    const unsigned bi = bestidx[row];
    unsigned idx = bi & 0x7fffffffu;
    if (bi >> 31) idx = (unsigned)(bestkey[row] & 0xffffffffull);
    const float4 q = *(const float4*)(cb + (size_t)idx * DIMS + d4 * 4);
    const float4 xv = *(const float4*)(x + (size_t)gid * 4);
    *(float4*)(out + (size_t)gid * 4) = q;
    const float dx = q.x - xv.x, dy = q.y - xv.y, dz = q.z - xv.z, dw = q.w - xv.w;
    s += dx * dx + dy * dy + dz * dz + dw * dw;
  }
#pragma unroll
  for (int m = 1; m < 64; m <<= 1) s += __shfl_xor(s, m);
  if ((threadIdx.x & 63) == 0) wsum[threadIdx.x >> 6] = s;
  __syncthreads();
  if (threadIdx.x == 0)
    partials[blockIdx.x] = wsum[0] + wsum[1] + wsum[2] + wsum[3];
}

// ---------------------------------------------------------------------------
// K6: final loss reduce.
// ---------------------------------------------------------------------------
__global__ void k_loss(const float* __restrict__ partials, float* __restrict__ loss_cell) {
  __shared__ double wsum[4];
  double s = 0.0;
#pragma unroll
  for (int i = 0; i < 8; ++i) s += (double)partials[i * 256 + threadIdx.x];
#pragma unroll
  for (int m = 1; m < 64; m <<= 1) s += __shfl_xor(s, m);
  if ((threadIdx.x & 63) == 0) wsum[threadIdx.x >> 6] = s;
  __syncthreads();
  if (threadIdx.x == 0)
    *loss_cell = (float)((wsum[0] + wsum[1] + wsum[2] + wsum[3]) *
                         (1.25 / (double)((size_t)NROWS * DIMS)));
}

// ---------------------------------------------------------------------------
extern "C" void kernel_launch(void* const* d_in, const int* in_sizes, int n_in,
                              void* d_out, int out_size, void* d_ws, size_t ws_size,
                              hipStream_t stream) {
  const float* x = (const float*)d_in[0];
  const float* cb = (const float*)d_in[1];
  float* out = (float*)d_out;
  char* ws = (char*)d_ws;

  float* cnorm = (float*)(ws + 0);                //  32 KB
  u64* pk1 = (u64*)(ws + 32768);                  // 512 KB [NH][NROWS]
  u64* pk2 = (u64*)(ws + 557056);                 // 512 KB
  float* d3h = (float*)(ws + 1081344);            // 256 KB
  unsigned* bestidx = (unsigned*)(ws + 1343488);  // 128 KB
  u64* bestkey = (u64*)(ws + 1474560);            // 256 KB
  int* wlist = (int*)(ws + 1736704);              // 128 KB
  int* slist = (int*)(ws + 1867776);              // 128 KB
  int* s2list = (int*)(ws + 1998848);             // 128 KB
  int* wcount = (int*)(ws + 2129920);
  int* scount = wcount + 1;
  float* partials = (float*)(ws + 2129984);       //   8 KB
  _Float16* cbh = (_Float16*)(ws + 2138176);      //   4 MB (fast path)
  float* loss_cell = out + (NROWS * DIMS);

  const bool fast = ws_size >= (size_t)(2138176 + KCODES * DIMS * 2);

  if (fast) {
    k_prep2<<<KCODES / 4, 256, 0, stream>>>(cb, cbh, cnorm, wcount, scount, loss_cell);
    k_gemm2<<<(NROWS / 256) * NH, 512, 0, stream>>>(x, cbh, cnorm, pk1, pk2, d3h);
  } else {
    k_cnorm<<<KCODES / 4, 256, 0, stream>>>(cb, cnorm, wcount, scount, loss_cell);
    k_gemm_fb<<<(NROWS / 256) * NH, 512, 0, stream>>>(x, cb, cnorm, pk1, pk2, d3h);
  }
  k_merge<<<NROWS / 256, 256, 0, stream>>>(pk1, pk2, d3h, bestidx, bestkey,
                                           wlist, wcount, slist, s2list, scount);
  k_soft<<<64, 256, 0, stream>>>(x, cb, slist, s2list, scount, bestidx);
  k_refine3<<<KCODES / 32, 512, 0, stream>>>(x, cb, wlist, wcount, bestkey);
  k_out2<<<2048, 256, 0, stream>>>(x, cb, bestidx, bestkey, out, partials);
  k_loss<<<1, 256, 0, stream>>>(partials, loss_cell);
}